// Round 1
// baseline (184.047 us; speedup 1.0000x reference)
//
#include <hip/hip_runtime.h>

// AdaptiveConv2d: hypernetwork MLP -> per-sample conv kernels, then
// per-sample 3x3 SAME conv + bias + relu, via bf16 implicit-GEMM MFMA.

typedef __bf16 bf16;
typedef __bf16 bf16x8 __attribute__((ext_vector_type(8)));
typedef float f32x4 __attribute__((ext_vector_type(4)));

#define NB 16     // batch
#define CI 64
#define CO 64
#define HH 128
#define WW 128
#define TS 16     // spatial tile (TS x TS)
#define HALO 18   // TS + 2
#define CPAD 72   // xt channel stride (pad 64->72: bank spread)
#define WPAD 72   // weight tile ci stride
#define NKW 36864 // CO*CI*9
#define NROWS 36928

// ---------------- hypernetwork ----------------
// grid 145 x 256. Each block recomputes h1 (tiny), each thread owns one W2
// row, loops over the 16 samples. Weights out as bf16 [b][tap][co][ci].
__global__ __launch_bounds__(256)
void hyper_kernel(const float* __restrict__ z, const float* __restrict__ W0,
                  const float* __restrict__ b0, const float* __restrict__ W1,
                  const float* __restrict__ b1, const float* __restrict__ W2,
                  const float* __restrict__ b2, bf16* __restrict__ wt,
                  float* __restrict__ biases) {
  __shared__ float h1s[NB][30];
  const int tid = threadIdx.x;
  if (tid < NB) {
    float h0[20];
    #pragma unroll
    for (int i = 0; i < 20; ++i) {
      float s = b0[i];
      #pragma unroll
      for (int j = 0; j < 16; ++j) s += W0[i * 16 + j] * z[tid * 16 + j];
      h0[i] = fmaxf(s, 0.f);
    }
    #pragma unroll
    for (int i = 0; i < 30; ++i) {
      float s = b1[i];
      #pragma unroll
      for (int j = 0; j < 20; ++j) s += W1[i * 20 + j] * h0[j];
      h1s[tid][i] = fmaxf(s, 0.f);
    }
  }
  __syncthreads();
  const int r = blockIdx.x * 256 + tid;
  if (r >= NROWS) return;
  float w2r[30];
  #pragma unroll
  for (int j = 0; j < 30; ++j) w2r[j] = W2[r * 30 + j];
  const float bb = b2[r];
  const bool isk = r < NKW;
  int co = 0, ci = 0, tap = 0;
  if (isk) {
    co = r / 576;
    int rem = r - co * 576;
    ci = rem / 9;
    tap = rem - ci * 9;
  }
  for (int b = 0; b < NB; ++b) {
    float s = bb;
    #pragma unroll
    for (int j = 0; j < 30; ++j) s += w2r[j] * h1s[b][j];
    s = fmaxf(s, 0.f);
    if (isk)
      wt[((size_t)((b * 9 + tap) * CO + co)) * CI + ci] = (bf16)s;
    else
      biases[b * CO + (r - NKW)] = s;
  }
}

// ---------------- conv (implicit GEMM, bf16 MFMA) ----------------
// block: 1 sample x 16x16 spatial tile x all 64 co. 1024 threads = 16 waves.
// Wave w: co-groups {2*(w&1), 2*(w&1)+1}, tile rows {2*(w>>1), 2*(w>>1)+1}.
// K = 9 taps x 64 ci, stepped as tap-major, 32-ci halves per MFMA.
__global__ __launch_bounds__(1024)
void conv_kernel(const float* __restrict__ x, const bf16* __restrict__ wt,
                 const float* __restrict__ bias, float* __restrict__ out) {
  __shared__ __align__(16) bf16 xt[HALO * HALO * CPAD];  // 46656 B
  __shared__ __align__(16) bf16 wts[CO * WPAD];          //  9216 B

  const int b = blockIdx.z;
  const int x0 = blockIdx.x * TS;
  const int y0 = blockIdx.y * TS;
  const int tid = threadIdx.x;

  // stage x tile (with halo) fp32 -> bf16, layout [py][px][ci(pad 72)]
  for (int e = tid; e < HALO * HALO * CI; e += 1024) {
    int ci = e / (HALO * HALO);
    int p = e - ci * (HALO * HALO);
    int py = p / HALO;
    int px = p - py * HALO;
    int gy = y0 + py - 1, gx = x0 + px - 1;
    float v = 0.f;
    if (gy >= 0 && gy < HH && gx >= 0 && gx < WW)
      v = x[((size_t)(b * CI + ci) * HH + gy) * WW + gx];
    xt[(py * HALO + px) * CPAD + ci] = (bf16)v;
  }

  const int lane = tid & 63;
  const int wv = tid >> 6;
  const int m = lane & 15;   // A row (co in group) / B col (pixel x)
  const int q = lane >> 4;   // quad
  const int cg0 = (wv & 1) * 2;
  const int ty0 = (wv >> 1) * 2;

  f32x4 acc[2][2];
  #pragma unroll
  for (int i = 0; i < 2; ++i)
    #pragma unroll
    for (int j = 0; j < 2; ++j) acc[i][j] = (f32x4){0.f, 0.f, 0.f, 0.f};

  // per-tap weight staging assignment
  const int wco = tid >> 4;
  const int wci = (tid & 15) * 4;
  const bf16* wsrc = wt + (size_t)b * 9 * CO * CI + (size_t)wco * CI + wci;

  for (int tap = 0; tap < 9; ++tap) {
    __syncthreads();  // previous tap's compute done (also covers xt at tap 0)
    *reinterpret_cast<uint2*>(&wts[wco * WPAD + wci]) =
        *reinterpret_cast<const uint2*>(wsrc + (size_t)tap * CO * CI);
    __syncthreads();
    const int dy = tap / 3, dx = tap - dy * 3;
    #pragma unroll
    for (int kh = 0; kh < 2; ++kh) {
      const int ci0 = kh * 32 + q * 8;
      bf16x8 a0 = *reinterpret_cast<const bf16x8*>(
          &wts[(cg0 * 16 + m) * WPAD + ci0]);
      bf16x8 a1 = *reinterpret_cast<const bf16x8*>(
          &wts[((cg0 + 1) * 16 + m) * WPAD + ci0]);
      bf16x8 bv0 = *reinterpret_cast<const bf16x8*>(
          &xt[((ty0 + dy) * HALO + (m + dx)) * CPAD + ci0]);
      bf16x8 bv1 = *reinterpret_cast<const bf16x8*>(
          &xt[((ty0 + 1 + dy) * HALO + (m + dx)) * CPAD + ci0]);
      acc[0][0] = __builtin_amdgcn_mfma_f32_16x16x32_bf16(a0, bv0, acc[0][0], 0, 0, 0);
      acc[0][1] = __builtin_amdgcn_mfma_f32_16x16x32_bf16(a0, bv1, acc[0][1], 0, 0, 0);
      acc[1][0] = __builtin_amdgcn_mfma_f32_16x16x32_bf16(a1, bv0, acc[1][0], 0, 0, 0);
      acc[1][1] = __builtin_amdgcn_mfma_f32_16x16x32_bf16(a1, bv1, acc[1][1], 0, 0, 0);
    }
  }

  // epilogue: C/D layout col=lane&15 (pixel x), row=q*4+reg (co in group)
  #pragma unroll
  for (int i = 0; i < 2; ++i) {
    #pragma unroll
    for (int j = 0; j < 2; ++j) {
      const int gy = y0 + ty0 + j;
      #pragma unroll
      for (int r = 0; r < 4; ++r) {
        const int co = (cg0 + i) * 16 + q * 4 + r;
        float v = acc[i][j][r] + bias[b * CO + co];
        out[((size_t)(b * CO + co) * HH + gy) * WW + x0 + m] = fmaxf(v, 0.f);
      }
    }
  }
}

extern "C" void kernel_launch(void* const* d_in, const int* in_sizes, int n_in,
                              void* d_out, int out_size, void* d_ws,
                              size_t ws_size, hipStream_t stream) {
  const float* x = (const float*)d_in[0];
  const float* z = (const float*)d_in[1];
  const float* W0 = (const float*)d_in[2];
  const float* b0 = (const float*)d_in[3];
  const float* W1 = (const float*)d_in[4];
  const float* b1 = (const float*)d_in[5];
  const float* W2 = (const float*)d_in[6];
  const float* b2 = (const float*)d_in[7];
  float* out = (float*)d_out;

  // ws layout: wt bf16 [16][9][64][64] (1,179,648 B) | biases f32 [16][64]
  bf16* wt = (bf16*)d_ws;
  float* biases = (float*)((char*)d_ws + (size_t)NB * 9 * CO * CI * 2);

  hipLaunchKernelGGL(hyper_kernel, dim3((NROWS + 255) / 256), dim3(256), 0,
                     stream, z, W0, b0, W1, b1, W2, b2, wt, biases);
  hipLaunchKernelGGL(conv_kernel, dim3(WW / TS, HH / TS, NB), dim3(1024), 0,
                     stream, x, wt, biases, out);
}